// Round 7
// baseline (283.992 us; speedup 1.0000x reference)
//
#include <hip/hip_runtime.h>

#define B_  4
#define S_  2048
#define D_  1024
#define N_  (B_*S_)
#define SCALE 0.03125f
#define NEGINF (-3.0e38f)

typedef unsigned short u16;
typedef __attribute__((ext_vector_type(8))) short short8;
typedef __attribute__((ext_vector_type(4))) float floatx4;

__device__ __forceinline__ u16 f2bf(float f) {           // RNE float->bf16
    unsigned int u = __float_as_uint(f);
    u += 0x7FFFu + ((u >> 16) & 1u);
    return (u16)(u >> 16);
}
__device__ __forceinline__ float bf2f(u16 h) {
    return __uint_as_float((unsigned int)h << 16);
}

__device__ __forceinline__ void gl_lds16(const void* g, void* l) {
    __builtin_amdgcn_global_load_lds(
        (const __attribute__((address_space(1))) unsigned int*)g,
        (__attribute__((address_space(3))) unsigned int*)l, 16, 0, 0);
}

// ---------------- casts ----------------
__global__ __launch_bounds__(256) void cast_x(const float* __restrict__ x, u16* __restrict__ xb) {
    size_t i = ((size_t)blockIdx.x * 256 + threadIdx.x) * 8;
    float4 a = *(const float4*)&x[i];
    float4 b = *(const float4*)&x[i + 4];
    short8 o;
    o[0]=f2bf(a.x); o[1]=f2bf(a.y); o[2]=f2bf(a.z); o[3]=f2bf(a.w);
    o[4]=f2bf(b.x); o[5]=f2bf(b.y); o[6]=f2bf(b.z); o[7]=f2bf(b.w);
    *(short8*)&xb[i] = o;
}

// W [K][N] fp32 -> Wt [N][K] bf16 (3 weights via z)
__global__ __launch_bounds__(256) void cast_wt(const float* __restrict__ Wq, const float* __restrict__ Wk,
                                               const float* __restrict__ Wv, u16* __restrict__ Wt) {
    const float* W = (blockIdx.z == 0) ? Wq : (blockIdx.z == 1) ? Wk : Wv;
    u16* Out = Wt + (size_t)blockIdx.z * D_ * D_;
    __shared__ float t[32][33];
    const int c = threadIdx.x & 31, r0 = threadIdx.x >> 5;
    const int i0 = blockIdx.y * 32, j0 = blockIdx.x * 32;
#pragma unroll
    for (int rr = 0; rr < 4; ++rr)
        t[r0 + rr * 8][c] = W[(size_t)(i0 + r0 + rr * 8) * D_ + j0 + c];
    __syncthreads();
#pragma unroll
    for (int rr = 0; rr < 4; ++rr)
        Out[(size_t)(j0 + r0 + rr * 8) * D_ + i0 + c] = f2bf(t[c][r0 + rr * 8]);
}

// ---------------- MFMA 16x16x32 NT-GEMM core (round-2 verified) ----------------
// C[128x128] = A[128xK] * B[128xK]^T.  LDS tiles [row][64], 8-elem-group XOR
// swizzle applied on the GLOBAL side (LDS dest must be lane*16-contiguous).
__device__ __forceinline__ void mfma_nt_loop(const u16* __restrict__ A, int lda,
                                             const u16* __restrict__ Bp, int ldb,
                                             int m0, int n0, int kext,
                                             u16* As, u16* Bs, floatx4 acc[4][4])
{
    const int tid  = threadIdx.x;
    const int lane = tid & 63;
    const int lr   = lane & 15, quad = lane >> 4;
    const int wm   = ((tid >> 6) & 1) * 64, wn = (tid >> 7) * 64;
    const int e    = tid * 8;

    for (int k0 = 0; k0 < kext; k0 += 64) {
        __syncthreads();
#pragma unroll
        for (int it = 0; it < 4; ++it) {
            int idx = it * 2048 + e;
            int row = idx >> 6;
            int cg  = (idx & 63) >> 3;
            int gc  = (cg ^ (row & 7)) << 3;   // swizzled global k-offset
            gl_lds16(&A [(size_t)(m0 + row) * lda + k0 + gc], &As[idx]);
            gl_lds16(&Bp[(size_t)(n0 + row) * ldb + k0 + gc], &Bs[idx]);
        }
        __syncthreads();
#pragma unroll
        for (int kk = 0; kk < 2; ++kk) {
            short8 af[4], bf[4];
            const int kg = kk * 4 + quad;
#pragma unroll
            for (int i = 0; i < 4; ++i) {
                int am = wm + i * 16 + lr;
                af[i] = *(const short8*)&As[am * 64 + ((kg ^ (am & 7)) << 3)];
                int bn = wn + i * 16 + lr;
                bf[i] = *(const short8*)&Bs[bn * 64 + ((kg ^ (bn & 7)) << 3)];
            }
#pragma unroll
            for (int i = 0; i < 4; ++i)
#pragma unroll
                for (int j = 0; j < 4; ++j)
                    acc[i][j] = __builtin_amdgcn_mfma_f32_16x16x32_bf16(af[i], bf[j], acc[i][j], 0, 0, 0);
        }
    }
}

// C/D layout (verified): col = lane&15, row = (lane>>4)*4 + reg
#define EPI_VARS                                              \
    const int lane = threadIdx.x & 63;                        \
    const int lr = lane & 15, quad = lane >> 4;               \
    const int wm = ((threadIdx.x >> 6) & 1) * 64, wn = (threadIdx.x >> 7) * 64;

// ---------------- K1: Q/K projection (branch-free, lean registers) ----------------
__global__ __launch_bounds__(256) void qk_mfma(const u16* __restrict__ xb, const u16* __restrict__ Wt,
                                               u16* __restrict__ Q, u16* __restrict__ K)
{
    __shared__ u16 As[8192], Bs[8192];
    const int z = blockIdx.z;
    const u16* Bp = Wt + (size_t)z * D_ * D_;
    u16* Out = (z == 0) ? Q : K;
    const int m0 = blockIdx.y * 128, n0 = blockIdx.x * 128;
    floatx4 acc[4][4];
#pragma unroll
    for (int i = 0; i < 4; ++i)
#pragma unroll
        for (int j = 0; j < 4; ++j) acc[i][j] = (floatx4){0.f, 0.f, 0.f, 0.f};
    mfma_nt_loop(xb, D_, Bp, D_, m0, n0, D_, As, Bs, acc);

    EPI_VARS
#pragma unroll
    for (int i = 0; i < 4; ++i)
#pragma unroll
        for (int j = 0; j < 4; ++j)
#pragma unroll
            for (int r = 0; r < 4; ++r)
                Out[(size_t)(m0 + wm + i * 16 + quad * 4 + r) * D_ + n0 + wn + j * 16 + lr] = f2bf(acc[i][j][r]);
}

// ---------------- K2: V projection, direct transposed store to Vt[b][e][s] ----------------
// A lane's 4 acc regs are 4 contiguous s at fixed e -> one aligned ushort4 store.
__global__ __launch_bounds__(256) void v_mfma(const u16* __restrict__ xb, const u16* __restrict__ Wt,
                                              u16* __restrict__ Vt)
{
    __shared__ u16 As[8192], Bs[8192];
    const int b = blockIdx.z;
    const int n0 = blockIdx.x * 128;            // e tile
    const int mloc = blockIdx.y * 128;          // s tile within batch
    const int m0 = b * S_ + mloc;               // row in flattened xb
    const u16* Bp = Wt + (size_t)2 * D_ * D_;
    u16* Vb = Vt + (size_t)b * D_ * S_;
    floatx4 acc[4][4];
#pragma unroll
    for (int i = 0; i < 4; ++i)
#pragma unroll
        for (int j = 0; j < 4; ++j) acc[i][j] = (floatx4){0.f, 0.f, 0.f, 0.f};
    mfma_nt_loop(xb, D_, Bp, D_, m0, n0, D_, As, Bs, acc);

    EPI_VARS
#pragma unroll
    for (int i = 0; i < 4; ++i)
#pragma unroll
        for (int j = 0; j < 4; ++j) {
            const int e  = n0 + wn + j * 16 + lr;
            const int s4 = mloc + wm + i * 16 + quad * 4;   // 4 contiguous s
            ushort4 o;
            o.x = f2bf(acc[i][j][0]); o.y = f2bf(acc[i][j][1]);
            o.z = f2bf(acc[i][j][2]); o.w = f2bf(acc[i][j][3]);
            *(ushort4*)&Vb[(size_t)e * S_ + s4] = o;        // 8B aligned (s4 % 4 == 0)
        }
}

// ---------------- K3: Sc = bf16(scale * Q K^T), packed causal triangle ----------------
__global__ __launch_bounds__(256) void scores_mfma(const u16* __restrict__ Q, const u16* __restrict__ K,
                                                   u16* __restrict__ Sc)
{
    const int t = blockIdx.x, b = blockIdx.z;
    int qt = (int)((sqrtf(8.0f * t + 1.0f) - 1.0f) * 0.5f);
    while ((qt + 1) * (qt + 2) / 2 <= t) ++qt;
    while (qt * (qt + 1) / 2 > t) --qt;
    const int kt = t - qt * (qt + 1) / 2;

    __shared__ u16 As[8192], Bs[8192];
    const u16* A  = Q + (size_t)b * S_ * D_;
    const u16* Bp = K + (size_t)b * S_ * D_;
    u16* Sb = Sc + (size_t)b * S_ * S_;
    const int m0 = qt * 128, n0 = kt * 128;
    floatx4 acc[4][4];
#pragma unroll
    for (int i = 0; i < 4; ++i)
#pragma unroll
        for (int j = 0; j < 4; ++j) acc[i][j] = (floatx4){0.f, 0.f, 0.f, 0.f};
    mfma_nt_loop(A, D_, Bp, D_, m0, n0, D_, As, Bs, acc);

    EPI_VARS
#pragma unroll
    for (int i = 0; i < 4; ++i)
#pragma unroll
        for (int r = 0; r < 4; ++r) {
            const int grow = m0 + wm + i * 16 + quad * 4 + r;
#pragma unroll
            for (int j = 0; j < 4; ++j) {
                const int gcol = n0 + wn + j * 16 + lr;
                const float v = (gcol <= grow) ? acc[i][j][r] * SCALE : NEGINF;
                Sb[(size_t)grow * S_ + gcol] = f2bf(v);
            }
        }
}

// ---------------- K4: row softmax, bf16 in -> bf16 P out (register-resident) ----------------
__global__ __launch_bounds__(256) void softmax_k(const u16* __restrict__ Sc, u16* __restrict__ P)
{
    const int row = blockIdx.x;
    const int b = row >> 11, q = row & (S_ - 1);
    const int L = ((q >> 7) + 1) << 7;           // 128-granular causal span
    const u16* rp = Sc + ((size_t)b * S_ + q) * S_;
    u16* pp = P + ((size_t)b * S_ + q) * S_;
    __shared__ float red[4];
    __shared__ float bc;
    const int tid = threadIdx.x;
    const int i = tid << 3;
    const bool act = i < L;

    float f[8];
    float lmax = -3.4e38f;
    if (act) {
        short8 v = *(const short8*)&rp[i];
#pragma unroll
        for (int k = 0; k < 8; ++k) { f[k] = bf2f((u16)v[k]); lmax = fmaxf(lmax, f[k]); }
    }
    for (int off = 32; off; off >>= 1) lmax = fmaxf(lmax, __shfl_down(lmax, off, 64));
    if ((tid & 63) == 0) red[tid >> 6] = lmax;
    __syncthreads();
    if (tid == 0) bc = fmaxf(fmaxf(red[0], red[1]), fmaxf(red[2], red[3]));
    __syncthreads();
    const float m = bc;

    float lsum = 0.f;
    if (act) {
#pragma unroll
        for (int k = 0; k < 8; ++k) { f[k] = __expf(f[k] - m); lsum += f[k]; }
    }
    for (int off = 32; off; off >>= 1) lsum += __shfl_down(lsum, off, 64);
    if ((tid & 63) == 0) red[tid >> 6] = lsum;
    __syncthreads();
    if (tid == 0) bc = red[0] + red[1] + red[2] + red[3];
    __syncthreads();
    const float inv = 1.0f / bc;

    if (act) {
        short8 o;
#pragma unroll
        for (int k = 0; k < 8; ++k) o[k] = (short)f2bf(f[k] * inv);
        *(short8*)&pp[i] = o;
    }
}

// ---------------- K5: O = P Vt^T, split-K (each block <= 1024 of K) ----------------
// y<8: qt=y, full causal span. y>=8: qt=8+(y-8)/2; even half -> K[0,1024) into out,
// odd half -> K[1024,(qt+1)*128) into O2 partials (folded by add_tail).
__global__ __launch_bounds__(256) void pv_mfma(const u16* __restrict__ P, const u16* __restrict__ Vt,
                                               float* __restrict__ O, float* __restrict__ O2)
{
    const int et = blockIdx.x, b = blockIdx.z;
    int qt, ks, ke, second;
    if (blockIdx.y < 8) { qt = blockIdx.y; ks = 0; ke = (qt + 1) * 128; second = 0; }
    else {
        const int idx = blockIdx.y - 8;
        qt = 8 + (idx >> 1); second = idx & 1;
        ks = second ? 1024 : 0;
        ke = second ? (qt + 1) * 128 : 1024;
    }
    __shared__ u16 As[8192], Bs[8192];
    const u16* A  = P  + (size_t)b * S_ * S_ + ks;   // shift K-window via base ptr
    const u16* Bp = Vt + (size_t)b * D_ * S_ + ks;
    const int m0 = qt * 128, n0 = et * 128;
    floatx4 acc[4][4];
#pragma unroll
    for (int i = 0; i < 4; ++i)
#pragma unroll
        for (int j = 0; j < 4; ++j) acc[i][j] = (floatx4){0.f, 0.f, 0.f, 0.f};
    mfma_nt_loop(A, S_, Bp, S_, m0, n0, ke - ks, As, Bs, acc);

    EPI_VARS
#pragma unroll
    for (int i = 0; i < 4; ++i)
#pragma unroll
        for (int r = 0; r < 4; ++r) {
            const int grow = m0 + wm + i * 16 + quad * 4 + r;
#pragma unroll
            for (int j = 0; j < 4; ++j) {
                const int gcol = n0 + wn + j * 16 + lr;
                if (second)
                    O2[((size_t)b * 1024 + (grow - 1024)) * D_ + gcol] = acc[i][j][r];
                else
                    O[((size_t)b * S_ + grow) * D_ + gcol] = acc[i][j][r];
            }
        }
}

// out[b][q][e] += O2[b][q-1024][e] for q in [1024,2048)
__global__ __launch_bounds__(256) void add_tail(float* __restrict__ out, const float* __restrict__ O2)
{
    size_t i = ((size_t)blockIdx.x * 256 + threadIdx.x) * 4;
    size_t b = i >> 20;                 // / (1024*1024)
    size_t rem = i & 1048575;
    float4 a = *(const float4*)&O2[i];
    float* d = &out[b * 2097152 + 1048576 + rem];
    float4 c = *(const float4*)d;
    c.x += a.x; c.y += a.y; c.z += a.z; c.w += a.w;
    *(float4*)d = c;
}

extern "C" void kernel_launch(void* const* d_in, const int* in_sizes, int n_in,
                              void* d_out, int out_size, void* d_ws, size_t ws_size,
                              hipStream_t stream) {
    const float* x  = (const float*)d_in[0];
    const float* Wq = (const float*)d_in[1];
    const float* Wk = (const float*)d_in[2];
    const float* Wv = (const float*)d_in[3];
    float* out = (float*)d_out;
    char* w = (char*)d_ws;

    // bytes: P bf16 [0,33.5M) aliases {xb [0,16.8M), Wt [16.8M,23.1M)} (xb/Wt dead after v_mfma)
    // Q [33.5M), K [50.3M), Vt [67.1M), Sc bf16 [83.9M,117.4M), O2 fp32 [117.4M,134.2M)
    u16* P  = (u16*)(w);
    u16* xb = (u16*)(w);
    u16* Wt = (u16*)(w + 16777216);
    u16* Q  = (u16*)(w + 33554432);
    u16* K  = (u16*)(w + 50331648);
    u16* Vt = (u16*)(w + 67108864);
    u16* Sc = (u16*)(w + 83886080);
    float* O2 = (float*)(w + 117440512);

    cast_x     <<<dim3(4096),        256, 0, stream>>>(x, xb);
    cast_wt    <<<dim3(32, 32, 3),   256, 0, stream>>>(Wq, Wk, Wv, Wt);
    qk_mfma    <<<dim3(8, 64, 2),    256, 0, stream>>>(xb, Wt, Q, K);
    v_mfma     <<<dim3(8, 16, B_),   256, 0, stream>>>(xb, Wt, Vt);
    scores_mfma<<<dim3(136, 1, B_),  256, 0, stream>>>(Q, K, Sc);
    softmax_k  <<<dim3(N_),          256, 0, stream>>>(Sc, P);
    pv_mfma    <<<dim3(8, 24, B_),   256, 0, stream>>>(P, Vt, out, O2);
    add_tail   <<<dim3(4096),        256, 0, stream>>>(out, O2);
}

// Round 8
// 278.355 us; speedup vs baseline: 1.0203x; 1.0203x over previous
//
#include <hip/hip_runtime.h>

#define B_  4
#define S_  2048
#define D_  1024
#define N_  (B_*S_)
#define SCALE 0.03125f
#define NEGINF (-3.0e38f)

typedef unsigned short u16;
typedef __attribute__((ext_vector_type(8))) short short8;
typedef __attribute__((ext_vector_type(4))) float floatx4;

__device__ __forceinline__ u16 f2bf(float f) {           // RNE float->bf16
    unsigned int u = __float_as_uint(f);
    u += 0x7FFFu + ((u >> 16) & 1u);
    return (u16)(u >> 16);
}
__device__ __forceinline__ float bf2f(u16 h) {
    return __uint_as_float((unsigned int)h << 16);
}

__device__ __forceinline__ void gl_lds16(const void* g, void* l) {
    __builtin_amdgcn_global_load_lds(
        (const __attribute__((address_space(1))) unsigned int*)g,
        (__attribute__((address_space(3))) unsigned int*)l, 16, 0, 0);
}

// ---------------- fused casts: x -> bf16 (blocks 0..4095), W -> Wt bf16 (blocks 4096..7167) ----------------
__global__ __launch_bounds__(256) void cast_fused(const float* __restrict__ x,
                                                  const float* __restrict__ Wq, const float* __restrict__ Wk,
                                                  const float* __restrict__ Wv,
                                                  u16* __restrict__ xb, u16* __restrict__ Wt) {
    __shared__ float t[32][33];
    if (blockIdx.x < 4096) {
        size_t i = ((size_t)blockIdx.x * 256 + threadIdx.x) * 8;
        float4 a = *(const float4*)&x[i];
        float4 b = *(const float4*)&x[i + 4];
        short8 o;
        o[0]=f2bf(a.x); o[1]=f2bf(a.y); o[2]=f2bf(a.z); o[3]=f2bf(a.w);
        o[4]=f2bf(b.x); o[5]=f2bf(b.y); o[6]=f2bf(b.z); o[7]=f2bf(b.w);
        *(short8*)&xb[i] = o;
    } else {
        const int tb = blockIdx.x - 4096;          // 0..3071
        const int z = tb >> 10, rem = tb & 1023;
        const float* W = (z == 0) ? Wq : (z == 1) ? Wk : Wv;
        u16* Out = Wt + (size_t)z * D_ * D_;
        const int c = threadIdx.x & 31, r0 = threadIdx.x >> 5;
        const int i0 = (rem >> 5) * 32, j0 = (rem & 31) * 32;
#pragma unroll
        for (int rr = 0; rr < 4; ++rr)
            t[r0 + rr * 8][c] = W[(size_t)(i0 + r0 + rr * 8) * D_ + j0 + c];
        __syncthreads();
#pragma unroll
        for (int rr = 0; rr < 4; ++rr)
            Out[(size_t)(j0 + r0 + rr * 8) * D_ + i0 + c] = f2bf(t[c][r0 + rr * 8]);
    }
}

// ---------------- MFMA 16x16x32 NT-GEMM core (round-2 verified) ----------------
// C[128x128] = A[128xK] * B[128xK]^T.  LDS tiles [row][64], 8-elem-group XOR
// swizzle applied on the GLOBAL side (LDS dest must be lane*16-contiguous).
__device__ __forceinline__ void mfma_nt_loop(const u16* __restrict__ A, int lda,
                                             const u16* __restrict__ Bp, int ldb,
                                             int m0, int n0, int kext,
                                             u16* As, u16* Bs, floatx4 acc[4][4])
{
    const int tid  = threadIdx.x;
    const int lane = tid & 63;
    const int lr   = lane & 15, quad = lane >> 4;
    const int wm   = ((tid >> 6) & 1) * 64, wn = (tid >> 7) * 64;
    const int e    = tid * 8;

    for (int k0 = 0; k0 < kext; k0 += 64) {
        __syncthreads();
#pragma unroll
        for (int it = 0; it < 4; ++it) {
            int idx = it * 2048 + e;
            int row = idx >> 6;
            int cg  = (idx & 63) >> 3;
            int gc  = (cg ^ (row & 7)) << 3;   // swizzled global k-offset
            gl_lds16(&A [(size_t)(m0 + row) * lda + k0 + gc], &As[idx]);
            gl_lds16(&Bp[(size_t)(n0 + row) * ldb + k0 + gc], &Bs[idx]);
        }
        __syncthreads();
#pragma unroll
        for (int kk = 0; kk < 2; ++kk) {
            short8 af[4], bf[4];
            const int kg = kk * 4 + quad;
#pragma unroll
            for (int i = 0; i < 4; ++i) {
                int am = wm + i * 16 + lr;
                af[i] = *(const short8*)&As[am * 64 + ((kg ^ (am & 7)) << 3)];
                int bn = wn + i * 16 + lr;
                bf[i] = *(const short8*)&Bs[bn * 64 + ((kg ^ (bn & 7)) << 3)];
            }
#pragma unroll
            for (int i = 0; i < 4; ++i)
#pragma unroll
                for (int j = 0; j < 4; ++j)
                    acc[i][j] = __builtin_amdgcn_mfma_f32_16x16x32_bf16(af[i], bf[j], acc[i][j], 0, 0, 0);
        }
    }
}

// C/D layout (verified): col = lane&15, row = (lane>>4)*4 + reg
#define EPI_VARS                                              \
    const int lane = threadIdx.x & 63;                        \
    const int lr = lane & 15, quad = lane >> 4;               \
    const int wm = ((threadIdx.x >> 6) & 1) * 64, wn = (threadIdx.x >> 7) * 64;

// ---------------- K1: Q/K/V projection, one 1536-block grid ----------------
// z<2: plain store. z==2: direct transposed Vt[b][e][s] store — a lane's 4 acc
// regs are 4 contiguous s at fixed e -> one aligned ushort4, no LDS, no VGPR bloat.
__global__ __launch_bounds__(256) void qkv_mfma(const u16* __restrict__ xb, const u16* __restrict__ Wt,
                                                u16* __restrict__ Q, u16* __restrict__ K, u16* __restrict__ Vt)
{
    __shared__ u16 As[8192], Bs[8192];
    const int z = blockIdx.z;
    const u16* Bp = Wt + (size_t)z * D_ * D_;
    const int m0 = blockIdx.y * 128, n0 = blockIdx.x * 128;
    floatx4 acc[4][4];
#pragma unroll
    for (int i = 0; i < 4; ++i)
#pragma unroll
        for (int j = 0; j < 4; ++j) acc[i][j] = (floatx4){0.f, 0.f, 0.f, 0.f};
    mfma_nt_loop(xb, D_, Bp, D_, m0, n0, D_, As, Bs, acc);

    EPI_VARS
    if (z < 2) {
        u16* Out = (z == 0) ? Q : K;
#pragma unroll
        for (int i = 0; i < 4; ++i)
#pragma unroll
            for (int j = 0; j < 4; ++j)
#pragma unroll
                for (int r = 0; r < 4; ++r)
                    Out[(size_t)(m0 + wm + i * 16 + quad * 4 + r) * D_ + n0 + wn + j * 16 + lr] = f2bf(acc[i][j][r]);
    } else {
        const int bb = m0 >> 11;                    // batch
        const int s0 = m0 & (S_ - 1);               // s-tile origin within batch
        u16* Vb = Vt + (size_t)bb * D_ * S_;
#pragma unroll
        for (int i = 0; i < 4; ++i)
#pragma unroll
            for (int j = 0; j < 4; ++j) {
                const int e  = n0 + wn + j * 16 + lr;
                const int s4 = s0 + wm + i * 16 + quad * 4;   // 4 contiguous s
                ushort4 o;
                o.x = f2bf(acc[i][j][0]); o.y = f2bf(acc[i][j][1]);
                o.z = f2bf(acc[i][j][2]); o.w = f2bf(acc[i][j][3]);
                *(ushort4*)&Vb[(size_t)e * S_ + s4] = o;      // 8B aligned (s4 % 4 == 0)
            }
    }
}

// ---------------- K2: Sc = bf16(scale * Q K^T), packed causal triangle ----------------
__global__ __launch_bounds__(256) void scores_mfma(const u16* __restrict__ Q, const u16* __restrict__ K,
                                                   u16* __restrict__ Sc)
{
    const int t = blockIdx.x, b = blockIdx.z;
    int qt = (int)((sqrtf(8.0f * t + 1.0f) - 1.0f) * 0.5f);
    while ((qt + 1) * (qt + 2) / 2 <= t) ++qt;
    while (qt * (qt + 1) / 2 > t) --qt;
    const int kt = t - qt * (qt + 1) / 2;

    __shared__ u16 As[8192], Bs[8192];
    const u16* A  = Q + (size_t)b * S_ * D_;
    const u16* Bp = K + (size_t)b * S_ * D_;
    u16* Sb = Sc + (size_t)b * S_ * S_;
    const int m0 = qt * 128, n0 = kt * 128;
    floatx4 acc[4][4];
#pragma unroll
    for (int i = 0; i < 4; ++i)
#pragma unroll
        for (int j = 0; j < 4; ++j) acc[i][j] = (floatx4){0.f, 0.f, 0.f, 0.f};
    mfma_nt_loop(A, D_, Bp, D_, m0, n0, D_, As, Bs, acc);

    EPI_VARS
#pragma unroll
    for (int i = 0; i < 4; ++i)
#pragma unroll
        for (int r = 0; r < 4; ++r) {
            const int grow = m0 + wm + i * 16 + quad * 4 + r;
#pragma unroll
            for (int j = 0; j < 4; ++j) {
                const int gcol = n0 + wn + j * 16 + lr;
                const float v = (gcol <= grow) ? acc[i][j][r] * SCALE : NEGINF;
                Sb[(size_t)grow * S_ + gcol] = f2bf(v);
            }
        }
}

// ---------------- K3: row softmax, bf16 in -> bf16 P out (register-resident) ----------------
__global__ __launch_bounds__(256) void softmax_k(const u16* __restrict__ Sc, u16* __restrict__ P)
{
    const int row = blockIdx.x;
    const int b = row >> 11, q = row & (S_ - 1);
    const int L = ((q >> 7) + 1) << 7;           // 128-granular causal span
    const u16* rp = Sc + ((size_t)b * S_ + q) * S_;
    u16* pp = P + ((size_t)b * S_ + q) * S_;
    __shared__ float red[4];
    __shared__ float bc;
    const int tid = threadIdx.x;
    const int i = tid << 3;
    const bool act = i < L;

    float f[8];
    float lmax = -3.4e38f;
    if (act) {
        short8 v = *(const short8*)&rp[i];
#pragma unroll
        for (int k = 0; k < 8; ++k) { f[k] = bf2f((u16)v[k]); lmax = fmaxf(lmax, f[k]); }
    }
    for (int off = 32; off; off >>= 1) lmax = fmaxf(lmax, __shfl_down(lmax, off, 64));
    if ((tid & 63) == 0) red[tid >> 6] = lmax;
    __syncthreads();
    if (tid == 0) bc = fmaxf(fmaxf(red[0], red[1]), fmaxf(red[2], red[3]));
    __syncthreads();
    const float m = bc;

    float lsum = 0.f;
    if (act) {
#pragma unroll
        for (int k = 0; k < 8; ++k) { f[k] = __expf(f[k] - m); lsum += f[k]; }
    }
    for (int off = 32; off; off >>= 1) lsum += __shfl_down(lsum, off, 64);
    if ((tid & 63) == 0) red[tid >> 6] = lsum;
    __syncthreads();
    if (tid == 0) bc = red[0] + red[1] + red[2] + red[3];
    __syncthreads();
    const float inv = 1.0f / bc;

    if (act) {
        short8 o;
#pragma unroll
        for (int k = 0; k < 8; ++k) o[k] = (short)f2bf(f[k] * inv);
        *(short8*)&pp[i] = o;
    }
}

// ---------------- K4: O = P Vt^T, split-K (each block <= 1024 of K) ----------------
// y<8: qt=y, full causal span. y>=8: qt=8+(y-8)/2; even half -> K[0,1024) into out,
// odd half -> K[1024,(qt+1)*128) into O2 partials (folded by add_tail).
__global__ __launch_bounds__(256) void pv_mfma(const u16* __restrict__ P, const u16* __restrict__ Vt,
                                               float* __restrict__ O, float* __restrict__ O2)
{
    const int et = blockIdx.x, b = blockIdx.z;
    int qt, ks, ke, second;
    if (blockIdx.y < 8) { qt = blockIdx.y; ks = 0; ke = (qt + 1) * 128; second = 0; }
    else {
        const int idx = blockIdx.y - 8;
        qt = 8 + (idx >> 1); second = idx & 1;
        ks = second ? 1024 : 0;
        ke = second ? (qt + 1) * 128 : 1024;
    }
    __shared__ u16 As[8192], Bs[8192];
    const u16* A  = P  + (size_t)b * S_ * S_ + ks;   // shift K-window via base ptr
    const u16* Bp = Vt + (size_t)b * D_ * S_ + ks;
    const int m0 = qt * 128, n0 = et * 128;
    floatx4 acc[4][4];
#pragma unroll
    for (int i = 0; i < 4; ++i)
#pragma unroll
        for (int j = 0; j < 4; ++j) acc[i][j] = (floatx4){0.f, 0.f, 0.f, 0.f};
    mfma_nt_loop(A, S_, Bp, S_, m0, n0, ke - ks, As, Bs, acc);

    EPI_VARS
#pragma unroll
    for (int i = 0; i < 4; ++i)
#pragma unroll
        for (int r = 0; r < 4; ++r) {
            const int grow = m0 + wm + i * 16 + quad * 4 + r;
#pragma unroll
            for (int j = 0; j < 4; ++j) {
                const int gcol = n0 + wn + j * 16 + lr;
                if (second)
                    O2[((size_t)b * 1024 + (grow - 1024)) * D_ + gcol] = acc[i][j][r];
                else
                    O[((size_t)b * S_ + grow) * D_ + gcol] = acc[i][j][r];
            }
        }
}

// out[b][q][e] += O2[b][q-1024][e] for q in [1024,2048)
__global__ __launch_bounds__(256) void add_tail(float* __restrict__ out, const float* __restrict__ O2)
{
    size_t i = ((size_t)blockIdx.x * 256 + threadIdx.x) * 4;
    size_t b = i >> 20;                 // / (1024*1024)
    size_t rem = i & 1048575;
    float4 a = *(const float4*)&O2[i];
    float* d = &out[b * 2097152 + 1048576 + rem];
    float4 c = *(const float4*)d;
    c.x += a.x; c.y += a.y; c.z += a.z; c.w += a.w;
    *(float4*)d = c;
}

extern "C" void kernel_launch(void* const* d_in, const int* in_sizes, int n_in,
                              void* d_out, int out_size, void* d_ws, size_t ws_size,
                              hipStream_t stream) {
    const float* x  = (const float*)d_in[0];
    const float* Wq = (const float*)d_in[1];
    const float* Wk = (const float*)d_in[2];
    const float* Wv = (const float*)d_in[3];
    float* out = (float*)d_out;
    char* w = (char*)d_ws;

    // bytes: P bf16 [0,33.5M) aliases {xb [0,16.8M), Wt [16.8M,23.1M)} (xb/Wt dead after qkv)
    // Q [33.5M), K [50.3M), Vt [67.1M), Sc bf16 [83.9M,117.4M), O2 fp32 [117.4M,134.2M)
    u16* P  = (u16*)(w);
    u16* xb = (u16*)(w);
    u16* Wt = (u16*)(w + 16777216);
    u16* Q  = (u16*)(w + 33554432);
    u16* K  = (u16*)(w + 50331648);
    u16* Vt = (u16*)(w + 67108864);
    u16* Sc = (u16*)(w + 83886080);
    float* O2 = (float*)(w + 117440512);

    cast_fused <<<dim3(7168),        256, 0, stream>>>(x, Wq, Wk, Wv, xb, Wt);
    qkv_mfma   <<<dim3(8, 64, 3),    256, 0, stream>>>(xb, Wt, Q, K, Vt);
    scores_mfma<<<dim3(136, 1, B_),  256, 0, stream>>>(Q, K, Sc);
    softmax_k  <<<dim3(N_),          256, 0, stream>>>(Sc, P);
    pv_mfma    <<<dim3(8, 24, B_),   256, 0, stream>>>(P, Vt, out, O2);
    add_tail   <<<dim3(4096),        256, 0, stream>>>(out, O2);
}

// Round 9
// 261.163 us; speedup vs baseline: 1.0874x; 1.0658x over previous
//
#include <hip/hip_runtime.h>

#define B_  4
#define S_  2048
#define D_  1024
#define N_  (B_*S_)
#define SCALE 0.03125f
#define NEGINF (-3.0e38f)

typedef unsigned short u16;
typedef __attribute__((ext_vector_type(8))) short short8;
typedef __attribute__((ext_vector_type(4))) float floatx4;

__device__ __forceinline__ u16 f2bf(float f) {           // RNE float->bf16
    unsigned int u = __float_as_uint(f);
    u += 0x7FFFu + ((u >> 16) & 1u);
    return (u16)(u >> 16);
}
__device__ __forceinline__ float bf2f(u16 h) {
    return __uint_as_float((unsigned int)h << 16);
}

__device__ __forceinline__ void gl_lds16(const void* g, void* l) {
    __builtin_amdgcn_global_load_lds(
        (const __attribute__((address_space(1))) unsigned int*)g,
        (__attribute__((address_space(3))) unsigned int*)l, 16, 0, 0);
}

// ---------------- fused casts ----------------
// blocks [0,4096): x cast. [4096,4608): Wq plain. [4608,5120): Wk plain.
// [5120,6144): Wv transposed 32x32 tiles -> Wvt[e][d].
__global__ __launch_bounds__(256) void cast_fused(const float* __restrict__ x,
                                                  const float* __restrict__ Wq, const float* __restrict__ Wk,
                                                  const float* __restrict__ Wv,
                                                  u16* __restrict__ xb, u16* __restrict__ Wqb,
                                                  u16* __restrict__ Wkb, u16* __restrict__ Wvt) {
    __shared__ float t[32][33];
    const int blk = blockIdx.x;
    if (blk < 5120) {
        const float* src; u16* dst; size_t i;
        if (blk < 4096)      { src = x;  dst = xb;  i = (size_t)blk * 2048; }
        else if (blk < 4608) { src = Wq; dst = Wqb; i = (size_t)(blk - 4096) * 2048; }
        else                 { src = Wk; dst = Wkb; i = (size_t)(blk - 4608) * 2048; }
        i += (size_t)threadIdx.x * 8;
        float4 a = *(const float4*)&src[i];
        float4 b = *(const float4*)&src[i + 4];
        short8 o;
        o[0]=f2bf(a.x); o[1]=f2bf(a.y); o[2]=f2bf(a.z); o[3]=f2bf(a.w);
        o[4]=f2bf(b.x); o[5]=f2bf(b.y); o[6]=f2bf(b.z); o[7]=f2bf(b.w);
        *(short8*)&dst[i] = o;
    } else {
        const int tb = blk - 5120;                 // 0..1023
        const int c = threadIdx.x & 31, r0 = threadIdx.x >> 5;
        const int i0 = (tb >> 5) * 32, j0 = (tb & 31) * 32;
#pragma unroll
        for (int rr = 0; rr < 4; ++rr)
            t[r0 + rr * 8][c] = Wv[(size_t)(i0 + r0 + rr * 8) * D_ + j0 + c];
        __syncthreads();
#pragma unroll
        for (int rr = 0; rr < 4; ++rr)
            Wvt[(size_t)(j0 + r0 + rr * 8) * D_ + i0 + c] = f2bf(t[c][r0 + rr * 8]);
    }
}

// ---------------- MFMA 16x16x32 NT-GEMM core (round-2 verified) ----------------
// C[128x128] = A[128xK] * B[128xK]^T.  LDS tiles [row][64], 8-elem-group XOR
// swizzle applied on the GLOBAL side (LDS dest must be lane*16-contiguous).
__device__ __forceinline__ void mfma_nt_loop(const u16* __restrict__ A, int lda,
                                             const u16* __restrict__ Bp, int ldb,
                                             int m0, int n0, int kext,
                                             u16* As, u16* Bs, floatx4 acc[4][4])
{
    const int tid  = threadIdx.x;
    const int lane = tid & 63;
    const int lr   = lane & 15, quad = lane >> 4;
    const int wm   = ((tid >> 6) & 1) * 64, wn = (tid >> 7) * 64;
    const int e    = tid * 8;

    for (int k0 = 0; k0 < kext; k0 += 64) {
        __syncthreads();
#pragma unroll
        for (int it = 0; it < 4; ++it) {
            int idx = it * 2048 + e;
            int row = idx >> 6;
            int cg  = (idx & 63) >> 3;
            int gc  = (cg ^ (row & 7)) << 3;   // swizzled global k-offset
            gl_lds16(&A [(size_t)(m0 + row) * lda + k0 + gc], &As[idx]);
            gl_lds16(&Bp[(size_t)(n0 + row) * ldb + k0 + gc], &Bs[idx]);
        }
        __syncthreads();
#pragma unroll
        for (int kk = 0; kk < 2; ++kk) {
            short8 af[4], bf[4];
            const int kg = kk * 4 + quad;
#pragma unroll
            for (int i = 0; i < 4; ++i) {
                int am = wm + i * 16 + lr;
                af[i] = *(const short8*)&As[am * 64 + ((kg ^ (am & 7)) << 3)];
                int bn = wn + i * 16 + lr;
                bf[i] = *(const short8*)&Bs[bn * 64 + ((kg ^ (bn & 7)) << 3)];
            }
#pragma unroll
            for (int i = 0; i < 4; ++i)
#pragma unroll
                for (int j = 0; j < 4; ++j)
                    acc[i][j] = __builtin_amdgcn_mfma_f32_16x16x32_bf16(af[i], bf[j], acc[i][j], 0, 0, 0);
        }
    }
}

// C/D layout (verified): col = lane&15, row = (lane>>4)*4 + reg
#define EPI_VARS                                              \
    const int lane = threadIdx.x & 63;                        \
    const int lr = lane & 15, quad = lane >> 4;               \
    const int wm = ((threadIdx.x >> 6) & 1) * 64, wn = (threadIdx.x >> 7) * 64;

// ---------------- K1: Mt = Wk *NT* Wq  (Mt[d'][d] = sum_e Wk[d'][e] Wq[d][e]) ----------------
__global__ __launch_bounds__(256) void mt_mfma(const u16* __restrict__ Wkb, const u16* __restrict__ Wqb,
                                               u16* __restrict__ Mt)
{
    __shared__ u16 As[8192], Bs[8192];
    const int m0 = blockIdx.y * 128, n0 = blockIdx.x * 128;
    floatx4 acc[4][4];
#pragma unroll
    for (int i = 0; i < 4; ++i)
#pragma unroll
        for (int j = 0; j < 4; ++j) acc[i][j] = (floatx4){0.f, 0.f, 0.f, 0.f};
    mfma_nt_loop(Wkb, D_, Wqb, D_, m0, n0, D_, As, Bs, acc);

    EPI_VARS
#pragma unroll
    for (int i = 0; i < 4; ++i)
#pragma unroll
        for (int j = 0; j < 4; ++j)
#pragma unroll
            for (int r = 0; r < 4; ++r)
                Mt[(size_t)(m0 + wm + i * 16 + quad * 4 + r) * D_ + n0 + wn + j * 16 + lr] = f2bf(acc[i][j][r]);
}

// ---------------- K2: y = x *NT* Mt  (y[s][d'] = sum_d x[s][d] Mt[d'][d]) ----------------
__global__ __launch_bounds__(256) void y_mfma(const u16* __restrict__ xb, const u16* __restrict__ Mt,
                                              u16* __restrict__ Y)
{
    __shared__ u16 As[8192], Bs[8192];
    const int m0 = blockIdx.y * 128, n0 = blockIdx.x * 128;
    floatx4 acc[4][4];
#pragma unroll
    for (int i = 0; i < 4; ++i)
#pragma unroll
        for (int j = 0; j < 4; ++j) acc[i][j] = (floatx4){0.f, 0.f, 0.f, 0.f};
    mfma_nt_loop(xb, D_, Mt, D_, m0, n0, D_, As, Bs, acc);

    EPI_VARS
#pragma unroll
    for (int i = 0; i < 4; ++i)
#pragma unroll
        for (int j = 0; j < 4; ++j)
#pragma unroll
            for (int r = 0; r < 4; ++r)
                Y[(size_t)(m0 + wm + i * 16 + quad * 4 + r) * D_ + n0 + wn + j * 16 + lr] = f2bf(acc[i][j][r]);
}

// ---------------- K3: V projection, direct transposed store to Vt[b][e][s] ----------------
__global__ __launch_bounds__(256) void v_mfma(const u16* __restrict__ xb, const u16* __restrict__ Wvt,
                                              u16* __restrict__ Vt)
{
    __shared__ u16 As[8192], Bs[8192];
    const int b = blockIdx.z;
    const int n0 = blockIdx.x * 128;            // e tile
    const int mloc = blockIdx.y * 128;          // s tile within batch
    const int m0 = b * S_ + mloc;               // row in flattened xb
    u16* Vb = Vt + (size_t)b * D_ * S_;
    floatx4 acc[4][4];
#pragma unroll
    for (int i = 0; i < 4; ++i)
#pragma unroll
        for (int j = 0; j < 4; ++j) acc[i][j] = (floatx4){0.f, 0.f, 0.f, 0.f};
    mfma_nt_loop(xb, D_, Wvt, D_, m0, n0, D_, As, Bs, acc);

    EPI_VARS
#pragma unroll
    for (int i = 0; i < 4; ++i)
#pragma unroll
        for (int j = 0; j < 4; ++j) {
            const int e  = n0 + wn + j * 16 + lr;
            const int s4 = mloc + wm + i * 16 + quad * 4;   // 4 contiguous s
            ushort4 o;
            o.x = f2bf(acc[i][j][0]); o.y = f2bf(acc[i][j][1]);
            o.z = f2bf(acc[i][j][2]); o.w = f2bf(acc[i][j][3]);
            *(ushort4*)&Vb[(size_t)e * S_ + s4] = o;        // 8B aligned (s4 % 4 == 0)
        }
}

// ---------------- K4: Sc = bf16(scale * Y x^T), packed causal triangle ----------------
__global__ __launch_bounds__(256) void scores_mfma(const u16* __restrict__ Y, const u16* __restrict__ xb,
                                                   u16* __restrict__ Sc)
{
    const int t = blockIdx.x, b = blockIdx.z;
    int qt = (int)((sqrtf(8.0f * t + 1.0f) - 1.0f) * 0.5f);
    while ((qt + 1) * (qt + 2) / 2 <= t) ++qt;
    while (qt * (qt + 1) / 2 > t) --qt;
    const int kt = t - qt * (qt + 1) / 2;

    __shared__ u16 As[8192], Bs[8192];
    const u16* A  = Y  + (size_t)b * S_ * D_;
    const u16* Bp = xb + (size_t)b * S_ * D_;
    u16* Sb = Sc + (size_t)b * S_ * S_;
    const int m0 = qt * 128, n0 = kt * 128;
    floatx4 acc[4][4];
#pragma unroll
    for (int i = 0; i < 4; ++i)
#pragma unroll
        for (int j = 0; j < 4; ++j) acc[i][j] = (floatx4){0.f, 0.f, 0.f, 0.f};
    mfma_nt_loop(A, D_, Bp, D_, m0, n0, D_, As, Bs, acc);

    EPI_VARS
#pragma unroll
    for (int i = 0; i < 4; ++i)
#pragma unroll
        for (int r = 0; r < 4; ++r) {
            const int grow = m0 + wm + i * 16 + quad * 4 + r;
#pragma unroll
            for (int j = 0; j < 4; ++j) {
                const int gcol = n0 + wn + j * 16 + lr;
                const float v = (gcol <= grow) ? acc[i][j][r] * SCALE : NEGINF;
                Sb[(size_t)grow * S_ + gcol] = f2bf(v);
            }
        }
}

// ---------------- K5: row softmax, bf16 in -> bf16 P out (register-resident) ----------------
__global__ __launch_bounds__(256) void softmax_k(const u16* __restrict__ Sc, u16* __restrict__ P)
{
    const int row = blockIdx.x;
    const int b = row >> 11, q = row & (S_ - 1);
    const int L = ((q >> 7) + 1) << 7;           // 128-granular causal span
    const u16* rp = Sc + ((size_t)b * S_ + q) * S_;
    u16* pp = P + ((size_t)b * S_ + q) * S_;
    __shared__ float red[4];
    __shared__ float bc;
    const int tid = threadIdx.x;
    const int i = tid << 3;
    const bool act = i < L;

    float f[8];
    float lmax = -3.4e38f;
    if (act) {
        short8 v = *(const short8*)&rp[i];
#pragma unroll
        for (int k = 0; k < 8; ++k) { f[k] = bf2f((u16)v[k]); lmax = fmaxf(lmax, f[k]); }
    }
    for (int off = 32; off; off >>= 1) lmax = fmaxf(lmax, __shfl_down(lmax, off, 64));
    if ((tid & 63) == 0) red[tid >> 6] = lmax;
    __syncthreads();
    if (tid == 0) bc = fmaxf(fmaxf(red[0], red[1]), fmaxf(red[2], red[3]));
    __syncthreads();
    const float m = bc;

    float lsum = 0.f;
    if (act) {
#pragma unroll
        for (int k = 0; k < 8; ++k) { f[k] = __expf(f[k] - m); lsum += f[k]; }
    }
    for (int off = 32; off; off >>= 1) lsum += __shfl_down(lsum, off, 64);
    if ((tid & 63) == 0) red[tid >> 6] = lsum;
    __syncthreads();
    if (tid == 0) bc = red[0] + red[1] + red[2] + red[3];
    __syncthreads();
    const float inv = 1.0f / bc;

    if (act) {
        short8 o;
#pragma unroll
        for (int k = 0; k < 8; ++k) o[k] = (short)f2bf(f[k] * inv);
        *(short8*)&pp[i] = o;
    }
}

// ---------------- K6: O = P Vt^T (causal K-extent), fp32 out ----------------
__global__ __launch_bounds__(256) void pv_mfma(const u16* __restrict__ P, const u16* __restrict__ Vt,
                                               float* __restrict__ O)
{
    const int et = blockIdx.x, qt = blockIdx.y, b = blockIdx.z;
    __shared__ u16 As[8192], Bs[8192];
    const u16* A  = P  + (size_t)b * S_ * S_;
    const u16* Bp = Vt + (size_t)b * D_ * S_;
    const int m0 = qt * 128, n0 = et * 128;
    const int kext = (qt + 1) * 128;
    floatx4 acc[4][4];
#pragma unroll
    for (int i = 0; i < 4; ++i)
#pragma unroll
        for (int j = 0; j < 4; ++j) acc[i][j] = (floatx4){0.f, 0.f, 0.f, 0.f};
    mfma_nt_loop(A, S_, Bp, S_, m0, n0, kext, As, Bs, acc);

    EPI_VARS
#pragma unroll
    for (int i = 0; i < 4; ++i)
#pragma unroll
        for (int r = 0; r < 4; ++r) {
            const int grow = m0 + wm + i * 16 + quad * 4 + r;
#pragma unroll
            for (int j = 0; j < 4; ++j)
                O[((size_t)b * S_ + grow) * D_ + n0 + wn + j * 16 + lr] = acc[i][j][r];
        }
}

extern "C" void kernel_launch(void* const* d_in, const int* in_sizes, int n_in,
                              void* d_out, int out_size, void* d_ws, size_t ws_size,
                              hipStream_t stream) {
    const float* x  = (const float*)d_in[0];
    const float* Wq = (const float*)d_in[1];
    const float* Wk = (const float*)d_in[2];
    const float* Wv = (const float*)d_in[3];
    float* out = (float*)d_out;
    char* w = (char*)d_ws;

    // workspace layout (bytes)
    u16* xb  = (u16*)(w);                    // 16.8 MB
    u16* Wqb = (u16*)(w + 16777216);         //  2 MB
    u16* Wkb = (u16*)(w + 18874368);         //  2 MB
    u16* Wvt = (u16*)(w + 20971520);         //  2 MB
    u16* Mt  = (u16*)(w + 23068672);         //  2 MB
    u16* Y   = (u16*)(w + 25165824);         // 16.8 MB
    u16* Vt  = (u16*)(w + 41943040);         // 16.8 MB
    u16* Sc  = (u16*)(w + 58720256);         // 33.5 MB
    u16* P   = (u16*)(w + 92274688);         // 33.5 MB

    cast_fused <<<dim3(6144),        256, 0, stream>>>(x, Wq, Wk, Wv, xb, Wqb, Wkb, Wvt);
    mt_mfma    <<<dim3(8, 8),        256, 0, stream>>>(Wkb, Wqb, Mt);
    y_mfma     <<<dim3(8, 64),       256, 0, stream>>>(xb, Mt, Y);
    v_mfma     <<<dim3(8, 16, B_),   256, 0, stream>>>(xb, Wvt, Vt);
    scores_mfma<<<dim3(136, 1, B_),  256, 0, stream>>>(Y, xb, Sc);
    softmax_k  <<<dim3(N_),          256, 0, stream>>>(Sc, P);
    pv_mfma    <<<dim3(8, 16, B_),   256, 0, stream>>>(P, Vt, out);
}